// Round 4
// baseline (245.301 us; speedup 1.0000x reference)
//
#include <hip/hip_runtime.h>

#define T_LEN  16384
#define LTAG   64
#define F_PER  14
#define CHUNK  32
#define NCHUNK (T_LEN / CHUNK)   // 512 -> 2 blocks/CU
#define BOS_ID 0
#define EOS_ID 1
#define NREG   6
#define REGSZ  833334      // 6 x 833334 >= 5,000,000 ; 3.33 MB/region -> L2-resident (proven)
#define WARM   48          // forward warm-up (proven)
#define WB     96          // backward warm-up for bp backtrack coalescence

typedef __attribute__((ext_vector_type(4))) int i4;

// workspace layout (bytes)
static constexpr size_t EM_OFF = 0;                                 // float[T*64] 4 MB
static constexpr size_t BP_OFF = EM_OFF + (size_t)T_LEN * 64 * 4;   // uchar[T*64] 1 MB
static constexpr size_t AE_OFF = BP_OFF + (size_t)T_LEN * 64;       // float[64]
static constexpr size_t AC_OFF = AE_OFF + 512;                      // double acc ; uint cnt

// ---------------------------------------------------------------------------
// K1: emissions  em[t,l] = sum_f w[feat[t,l,f]]  (fp32)
// Region-sweep gather, NREG=6 (3.33 MB regions, L2-resident -- measured
// optimum: NREG=10 108us, NREG=6 88us, NREG=3 118us/L2-overflow).
// Block 0 also zeroes the score accumulator/ticket used by k_backtrack.
// ---------------------------------------------------------------------------
__global__ __launch_bounds__(256) void k_emissions(
    const int* __restrict__ idx, const float* __restrict__ w, float* __restrict__ em,
    double* __restrict__ acc, unsigned int* __restrict__ cnt)
{
    __shared__ int sIdx[256 * F_PER];          // 14 KB
    const int tid = threadIdx.x;
    if (blockIdx.x == 0 && tid == 0) { *acc = 0.0; *cnt = 0u; }
    const int* g = idx + (size_t)blockIdx.x * (256 * F_PER);
    for (int x = tid * 4; x < 256 * F_PER; x += 1024)
        *(i4*)(sIdx + x) = __builtin_nontemporal_load((const i4*)(g + x));
    __syncthreads();
    int id[F_PER];
#pragma unroll
    for (int f = 0; f < F_PER; ++f) id[f] = sIdx[tid * F_PER + f];
    float sf[F_PER];
#pragma unroll
    for (int f = 0; f < F_PER; ++f) sf[f] = 0.f;
    for (int r = 0; r < NREG; ++r) {
        const int lo = r * REGSZ;
#pragma unroll
        for (int f = 0; f < F_PER; ++f)
            if ((unsigned)(id[f] - lo) < (unsigned)REGSZ) sf[f] += w[id[f]];
    }
    float s = 0.f;
#pragma unroll
    for (int f = 0; f < F_PER; f += 2) s += sf[f] + sf[f + 1];
    em[(size_t)blockIdx.x * 256 + tid] = s;
}

// ---------------------------------------------------------------------------
// K2: forward Viterbi with self-warm. CHUNK=32 (A/B vs 16): per-CU total
// step count drops 256 -> 160 step-waves; discriminates the per-CU-shared-
// resource hypothesis (LDS pipe / L1-TA) from per-SIMD issue. 2-deep em
// prefetch covers the ~600cy MALL latency (em is L2-flushed between kernels).
// ---------------------------------------------------------------------------
__global__ __launch_bounds__(64, 1) void k_phase3(
    const float* __restrict__ trans, const float* __restrict__ em,
    unsigned char* __restrict__ bp, float* __restrict__ aEnd)
{
    __shared__ __align__(16) float sa[64];
    const int c = blockIdx.x;
    const int tid = threadIdx.x;                 // = state j
    const int t0 = c * CHUNK;
    int nsteps = (T_LEN - 1) - t0; if (nsteps > CHUNK) nsteps = CHUNK;

    float tr_[64];                               // T[i][tid], i = 0..63
#pragma unroll
    for (int i = 0; i < 64; ++i) tr_[i] = trans[i * 64 + tid];

    float a; int tw;
    if (t0 <= WARM) { tw = 0; a = tr_[BOS_ID] + em[tid]; }   // exact init at t=0
    else            { tw = t0 - WARM; a = em[(size_t)tw * 64 + tid]; } // neutral init

    // 2-deep emission prefetch pipeline
    float e_nxt = em[(size_t)(tw + 1) * 64 + tid];
    int tn2 = tw + 2; if (tn2 > T_LEN - 1) tn2 = T_LEN - 1;
    float e_nx2 = em[(size_t)tn2 * 64 + tid];
    const float4* ap = (const float4*)sa;

    // warm (or exact-replay) steps: no backpointers
    for (int t = tw + 1; t <= t0; ++t) {
        const float e = e_nxt;
        e_nxt = e_nx2;
        tn2 = t + 2; if (tn2 > T_LEN - 1) tn2 = T_LEN - 1;
        e_nx2 = em[(size_t)tn2 * 64 + tid];
        sa[tid] = a;
        float m = -3.0e38f;
#pragma unroll
        for (int g = 0; g < 4; ++g) {
            const float4 v0 = ap[4*g+0], v1 = ap[4*g+1], v2 = ap[4*g+2], v3 = ap[4*g+3];
            float s0[16];
            s0[0]  = tr_[16*g+0]  + v0.x;  s0[1]  = tr_[16*g+1]  + v0.y;
            s0[2]  = tr_[16*g+2]  + v0.z;  s0[3]  = tr_[16*g+3]  + v0.w;
            s0[4]  = tr_[16*g+4]  + v1.x;  s0[5]  = tr_[16*g+5]  + v1.y;
            s0[6]  = tr_[16*g+6]  + v1.z;  s0[7]  = tr_[16*g+7]  + v1.w;
            s0[8]  = tr_[16*g+8]  + v2.x;  s0[9]  = tr_[16*g+9]  + v2.y;
            s0[10] = tr_[16*g+10] + v2.z;  s0[11] = tr_[16*g+11] + v2.w;
            s0[12] = tr_[16*g+12] + v3.x;  s0[13] = tr_[16*g+13] + v3.y;
            s0[14] = tr_[16*g+14] + v3.z;  s0[15] = tr_[16*g+15] + v3.w;
#pragma unroll
            for (int st = 8; st >= 1; st >>= 1)
#pragma unroll
                for (int i = 0; i < st; ++i) s0[i] = fmaxf(s0[i], s0[i + st]);
            m = fmaxf(m, s0[0]);
        }
        a = e + m;
    }

    // real steps: emit backpointers (first-max semantics = jnp.argmax)
    const int tend = t0 + nsteps;
    for (int t = t0 + 1; t <= tend; ++t) {
        const float e = e_nxt;
        e_nxt = e_nx2;
        tn2 = t + 2; if (tn2 > T_LEN - 1) tn2 = T_LEN - 1;
        e_nx2 = em[(size_t)tn2 * 64 + tid];
        sa[tid] = a;
        float m = -3.0e38f; int bi = 0;
#pragma unroll
        for (int g = 0; g < 4; ++g) {
            const float4 v0 = ap[4*g+0], v1 = ap[4*g+1], v2 = ap[4*g+2], v3 = ap[4*g+3];
            float s0[16];
            s0[0]  = tr_[16*g+0]  + v0.x;  s0[1]  = tr_[16*g+1]  + v0.y;
            s0[2]  = tr_[16*g+2]  + v0.z;  s0[3]  = tr_[16*g+3]  + v0.w;
            s0[4]  = tr_[16*g+4]  + v1.x;  s0[5]  = tr_[16*g+5]  + v1.y;
            s0[6]  = tr_[16*g+6]  + v1.z;  s0[7]  = tr_[16*g+7]  + v1.w;
            s0[8]  = tr_[16*g+8]  + v2.x;  s0[9]  = tr_[16*g+9]  + v2.y;
            s0[10] = tr_[16*g+10] + v2.z;  s0[11] = tr_[16*g+11] + v2.w;
            s0[12] = tr_[16*g+12] + v3.x;  s0[13] = tr_[16*g+13] + v3.y;
            s0[14] = tr_[16*g+14] + v3.z;  s0[15] = tr_[16*g+15] + v3.w;
            float t16[16];
#pragma unroll
            for (int i = 0; i < 16; ++i) t16[i] = s0[i];
#pragma unroll
            for (int st = 8; st >= 1; st >>= 1)
#pragma unroll
                for (int i = 0; i < st; ++i) t16[i] = fmaxf(t16[i], t16[i + st]);
            const float gm = t16[0];
            int gb = 15;                          // first index attaining gm
#pragma unroll
            for (int i = 14; i >= 0; --i) gb = (s0[i] == gm) ? i : gb;
            if (gm > m) { m = gm; bi = 16*g + gb; }   // strict > keeps first group
        }
        a = e + m;
        bp[(size_t)t * 64 + tid] = (unsigned char)bi;
    }
    if (c == NCHUNK - 1) aEnd[tid] = a;          // alpha at t = 16383
}

// ---------------------------------------------------------------------------
// K3: per-chunk warm backtrack -> path + EXACT fp64 score terms.
// Final reduction folded in via device-scope f64 atomic + ticket (replaces
// k_sfin): each block adds its partial; the last-finishing block publishes
// out[0]. acc/cnt zeroed by k_emissions earlier in the same stream.
// ---------------------------------------------------------------------------
__global__ __launch_bounds__(64) void k_backtrack(
    const float* __restrict__ trans, const float* __restrict__ em,
    const unsigned char* __restrict__ bp, const float* __restrict__ aEnd,
    float* __restrict__ out, double* __restrict__ acc, unsigned int* __restrict__ cnt)
{
    __shared__ __align__(16) unsigned char sbp[(CHUNK + WB) * 64];   // 8 KB
    const int c = blockIdx.x;
    const int tid = threadIdx.x;
    const int t0 = c * CHUNK;
    int nsteps = (T_LEN - 1) - t0; if (nsteps > CHUNK) nsteps = CHUNK;
    int t_hi = t0 + nsteps + WB; if (t_hi > T_LEN - 1) t_hi = T_LEN - 1;
    const int nrows = t_hi - t0;                 // bp rows t0+1 .. t_hi

    // stage bp window into LDS (coalesced 16B loads)
    const unsigned char* gsrc = bp + (size_t)(t0 + 1) * 64;
    for (int x = tid * 16; x < nrows * 64; x += 1024)
        *(i4*)(sbp + x) = *(const i4*)(gsrc + x);

    // final tag: argmax_j aEnd[j] + T[j][EOS], first-occurrence tie-break
    float val = aEnd[tid] + trans[tid * 64 + EOS_ID];
    int idx = tid;
#pragma unroll
    for (int o = 32; o >= 1; o >>= 1) {
        float ov = __shfl_xor(val, o);
        int   oi = __shfl_xor(idx, o);
        if (ov > val || (ov == val && oi < idx)) { val = ov; idx = oi; }
    }
    __syncthreads();

    // walk down; all lanes follow the same tag (broadcast LDS reads).
    int tag = (t_hi == T_LEN - 1) ? idx : 0;
    int pp = 0, pt = 0;
    for (int t = t_hi; t > t0; --t) {
        const int r = t - t0;
        if (tid == r)     pp = tag;
        if (tid + 1 == r) pt = tag;
        tag = sbp[(r - 1) * 64 + tag];
    }
    if (tid == 0) pp = tag;                      // tag at t0

    // path writes
    if (tid < nsteps) out[1 + t0 + tid] = (float)pp;
    if (c == NCHUNK - 1 && tid == nsteps) out[1 + (T_LEN - 1)] = (float)pp;

    // exact fp64 score terms for t in (t0, t0+nsteps]
    double term = 0.0;
    if (tid < nsteps) {
        const int t = t0 + 1 + tid;
        term = (double)trans[pp * 64 + pt] + (double)em[(size_t)t * 64 + pt];
    }
    if (c == 0 && tid == 0)
        term += (double)trans[BOS_ID * 64 + pp] + (double)em[pp];
    if (c == NCHUNK - 1 && tid == nsteps)
        term += (double)trans[pp * 64 + EOS_ID];
#pragma unroll
    for (int o = 1; o < 64; o <<= 1) term += __shfl_xor(term, o);

    if (tid == 0) {
        atomicAdd(acc, term);
        __threadfence();
        const unsigned int old = atomicAdd(cnt, 1u);
        if (old == (unsigned int)(NCHUNK - 1)) {
            const double tot = atomicAdd(acc, 0.0);   // coherent read-back
            out[0] = (float)tot;
        }
    }
}

// ---------------------------------------------------------------------------
extern "C" void kernel_launch(void* const* d_in, const int* in_sizes, int n_in,
                              void* d_out, int out_size, void* d_ws, size_t ws_size,
                              hipStream_t stream)
{
    const int*   feat = (const int*)d_in[0];
    const float* w    = (const float*)d_in[1];
    const float* tr   = (const float*)d_in[2];
    float* out = (float*)d_out;
    char*  ws  = (char*)d_ws;

    float*         em  = (float*)(ws + EM_OFF);
    unsigned char* bp  = (unsigned char*)(ws + BP_OFF);
    float*         ae  = (float*)(ws + AE_OFF);
    double*        acc = (double*)(ws + AC_OFF);
    unsigned int*  cnt = (unsigned int*)(ws + AC_OFF + 8);

    k_emissions <<<(T_LEN * LTAG) / 256, 256, 0, stream>>>(feat, w, em, acc, cnt);
    k_phase3    <<<NCHUNK, 64, 0, stream>>>(tr, em, bp, ae);
    k_backtrack <<<NCHUNK, 64, 0, stream>>>(tr, em, bp, ae, out, acc, cnt);
}